// Round 21
// baseline (194.422 us; speedup 1.0000x reference)
//
#include <hip/hip_runtime.h>

#define N_NODES 100000
#define NBKT 782              // ceil(100000/128) buckets of 128 dst nodes
#define EPB 4096              // edges per partition block (r19: 1.5 blk/CU sweet spot)
#define BCAP 2560             // padded bucket capacity (mean 2048, +11 sigma)
#define NSL 4                 // fp8 y1 slices of 32 cols (32B rows, 3.2MB/slice < 4MB L2)
#define SL_U 800000           // uints per fp8 slice = N_NODES*8
#define Y2N (N_NODES * 8)     // floats per y2 partial slice

typedef unsigned int uint;
typedef unsigned short ushort;
typedef __attribute__((ext_vector_type(8))) short bf16x8;   // 8 bf16 (4 VGPRs)
typedef __attribute__((ext_vector_type(4))) float f32x4;    // MFMA acc
typedef __attribute__((ext_vector_type(2))) float f32x2;    // fp8 unpack pair

union FragU { uint4 u; bf16x8 b; };

// ---------- bf16 helpers ------------------------------------------------------
__device__ __forceinline__ uint pack_bf16_2(float a, float b) {
    uint ua = __float_as_uint(a), ub = __float_as_uint(b);
    ua += 0x7fff + ((ua >> 16) & 1);           // RNE
    ub += 0x7fff + ((ub >> 16) & 1);
    return (ua >> 16) | (ub & 0xffff0000u);
}
__device__ __forceinline__ float bf_lo(uint u) { return __uint_as_float(u << 16); }
__device__ __forceinline__ float bf_hi(uint u) { return __uint_as_float(u & 0xffff0000u); }

// ---------- edge-index access (handles int32 or raw int64 little-endian) ----
__device__ __forceinline__ int edge_at(const int* __restrict__ ei, int idx, int is64) {
    return is64 ? ei[2 * idx] : ei[idx];
}

// ---------- kZ: zero bucket cursors (4 blocks) + dtype probe (block 0) -------
__global__ __launch_bounds__(256) void kZ(const int* __restrict__ ei,
                                          int* __restrict__ cursor,
                                          int* __restrict__ gflag) {
    __shared__ int shp;
    int t = threadIdx.x;
    int b = blockIdx.x;
    for (int i = b * 256 + t; i < NBKT; i += 1024) cursor[i] = 0;
    if (b == 0) {
        if (t == 0) shp = 0;
        __syncthreads();
        int any = 0;
        for (int j = t; j < 4096; j += 256) any |= ei[2 * j + 1];
        if (any) atomicOr(&shp, 1);
        __syncthreads();
        if (t == 0) gflag[0] = shp;            // 0 => int64 little-endian layout
    }
}

// ---------- kP: single-pass partition into PADDED buckets --------------------
__global__ __launch_bounds__(256) void kP(const int* __restrict__ ei, int E,
                                          const int* __restrict__ gflag,
                                          int* __restrict__ cursor,
                                          uint* __restrict__ bkt_data) {
    __shared__ int h[NBKT];                   // per-block histogram / rank
    __shared__ int base[NBKT];                // this block's chunk base
    int t = threadIdx.x;
    int is64 = (gflag[0] == 0);
    for (int i = t; i < NBKT; i += 256) h[i] = 0;
    __syncthreads();
    int lo = blockIdx.x * EPB;
    int end = min(lo + EPB, E);
    for (int e = lo + t; e < end; e += 256) {
        int d = edge_at(ei, E + e, is64);
        atomicAdd(&h[d >> 7], 1);
    }
    __syncthreads();
    for (int i = t; i < NBKT; i += 256) {
        int c = h[i];
        base[i] = c ? atomicAdd(&cursor[i], c) : 0;
    }
    __syncthreads();
    for (int i = t; i < NBKT; i += 256) h[i] = 0;   // reuse as local rank
    __syncthreads();
    for (int e = lo + t; e < end; e += 256) {
        int d = edge_at(ei, E + e, is64);
        int s = edge_at(ei, e, is64);
        int b = d >> 7;
        int r = atomicAdd(&h[b], 1);
        int pos = base[b] + r;
        if (pos < BCAP)                        // 11-sigma guard (never fires)
            bkt_data[(size_t)b * BCAP + pos] = ((uint)s << 7) | (uint)(d & 127);
    }
}

// ---------- kB: per-bucket CSR build + degrees + dis -------------------------
__global__ __launch_bounds__(256) void kB(const uint* __restrict__ bkt_data,
                                          const int* __restrict__ cursor,
                                          int* __restrict__ srcs,
                                          int* __restrict__ count,
                                          int* __restrict__ offs,
                                          float* __restrict__ dis) {
    __shared__ int lc[128];    // local degree
    __shared__ int sc[128];    // inclusive scan
    __shared__ int lcur[128];  // local fill cursor
    int t = threadIdx.x;
    int b = blockIdx.x;
    if (t < 128) { lc[t] = 0; lcur[t] = 0; }
    __syncthreads();
    int start = b * BCAP;
    int n = min(cursor[b], BCAP);
    for (int i = t; i < n; i += 256)
        atomicAdd(&lc[bkt_data[start + i] & 127], 1);
    __syncthreads();
    if (t < 128) sc[t] = lc[t];
    __syncthreads();
    for (int d = 1; d < 128; d <<= 1) {
        int y = 0;
        if (t < 128 && t >= d) y = sc[t - d];
        __syncthreads();
        if (t < 128) sc[t] += y;
        __syncthreads();
    }
    if (t < 128) {
        int node = b * 128 + t;
        if (node < N_NODES) {
            int c = lc[t];
            count[node] = c;
            offs[node] = start + sc[t] - c;
            dis[node] = rsqrtf((float)c + 1.0f);
        }
    }
    __syncthreads();
    for (int i = t; i < n; i += 256) {
        uint rec = bkt_data[start + i];
        int dl = rec & 127;
        int r = atomicAdd(&lcur[dl], 1);
        srcs[start + (sc[dl] - lc[dl]) + r] = rec >> 7;
    }
}

// ---------- GEMM1 (MFMA bf16 -> fp8 store): y1s = e4m3((x@W1)*dis), 4 slices -
// Slice = 32 cols x 1B = 32B rows: agg1s does 2 dwordx4 in ONE 64B line.
__global__ __launch_bounds__(256) void k_gemm1(const float* __restrict__ x,
                                               const float* __restrict__ W,
                                               const float* __restrict__ dis,
                                               uint* __restrict__ y1s) {
    __shared__ uint4 WtA[2048];               // 32 KB
    char* wt = (char*)WtA;
    int t = threadIdx.x;

    const float4* W4 = (const float4*)W;
#pragma unroll
    for (int ii = 0; ii < 4; ++ii) {
        int tile = t + 256 * ii;              // 1024 (nq,kq) 4x4 tiles
        int nq = tile >> 5, kq = tile & 31;
        float4 r0 = W4[(4 * kq + 0) * 32 + nq];
        float4 r1 = W4[(4 * kq + 1) * 32 + nq];
        float4 r2 = W4[(4 * kq + 2) * 32 + nq];
        float4 r3 = W4[(4 * kq + 3) * 32 + nq];
        const float* p0 = (const float*)&r0;
        const float* p1 = (const float*)&r1;
        const float* p2 = (const float*)&r2;
        const float* p3 = (const float*)&r3;
#pragma unroll
        for (int cc = 0; cc < 4; ++cc) {
            int n = 4 * nq + cc;
            uint2 v;
            v.x = pack_bf16_2(p0[cc], p1[cc]);
            v.y = pack_bf16_2(p2[cc], p3[cc]);
            *(uint2*)(wt + n * 256 + (((kq >> 1) ^ (n & 7)) << 4) + ((kq & 1) << 3)) = v;
        }
    }
    __syncthreads();

    int w = t >> 6, lane = t & 63;
    int m = lane & 15, kg = lane >> 4;
    int row0 = blockIdx.x * 64 + 16 * w;

    int arow = row0 + m;
    bool av = arow < N_NODES;
    const float4* xr = (const float4*)(x + (size_t)arow * 128);
    float4 z4 = make_float4(0.f, 0.f, 0.f, 0.f);
    FragU af[4];
#pragma unroll
    for (int kf = 0; kf < 4; ++kf) {
        float4 g0 = av ? xr[8 * kf + 2 * kg]     : z4;
        float4 g1 = av ? xr[8 * kf + 2 * kg + 1] : z4;
        const float* a0 = (const float*)&g0;
        const float* a1 = (const float*)&g1;
        af[kf].u.x = pack_bf16_2(a0[0], a0[1]);
        af[kf].u.y = pack_bf16_2(a0[2], a0[3]);
        af[kf].u.z = pack_bf16_2(a1[0], a1[1]);
        af[kf].u.w = pack_bf16_2(a1[2], a1[3]);
    }

    int crow = row0 + 4 * kg;
    float dd[4];
#pragma unroll
    for (int rr = 0; rr < 4; ++rr)
        dd[rr] = (crow + rr < N_NODES) ? dis[crow + rr] : 0.0f;

    char* yb = (char*)y1s;
#pragma unroll
    for (int ct = 0; ct < 8; ++ct) {          // 16-col tile; slice = ct>>1
        f32x4 acc = {0.f, 0.f, 0.f, 0.f};
#pragma unroll
        for (int kf = 0; kf < 4; ++kf) {
            int n = 16 * ct + m;              // B col = lane&15
            bf16x8 bw = *(const bf16x8*)(wt + n * 256 + ((((kf << 2) | kg) ^ (n & 7)) << 4));
            acc = __builtin_amdgcn_mfma_f32_16x16x32_bf16(af[kf].b, bw, acc, 0, 0, 0);
        }
#pragma unroll
        for (int rr = 0; rr < 4; ++rr) {
            float v = acc[rr] * dd[rr];
            float p = __shfl_xor(v, 1, 64);   // partner col (odd)
            if (!(lane & 1)) {
                int grow = crow + rr;
                if (grow < N_NODES) {
                    uint pk = __builtin_amdgcn_cvt_pk_fp8_f32(v, p, 0, false);
                    *(ushort*)(yb + (size_t)(ct >> 1) * (SL_U * 4)
                               + (size_t)grow * 32 + (ct & 1) * 16 + m) = (ushort)pk;
                }
            }
        }
    }
}

// ---------- Aggregation 1 (4 fp8 slices, 32B rows = 1 line/edge) -------------
// slice = blockIdx.x % 4. 8-lane group per node, EDGE-PER-LANE; each edge
// reads 2 dwordx4 from the SAME 64B line -> 6.8M line-touches (halved vs 8
// slices). No prefetch (r15: null; keep VGPR low). Plain stores to y2p[slice]
// (r20: no cross-XCD atomics). Reduce-scatter/epilogue = r12's verified form.
__global__ __launch_bounds__(256) void k_agg1s(const uint* __restrict__ y1s,
                                               const int* __restrict__ srcs,
                                               const int* __restrict__ offs,
                                               const int* __restrict__ count,
                                               const float* __restrict__ dis,
                                               const float* __restrict__ b1,
                                               const float* __restrict__ W2,
                                               float* __restrict__ y2p) {
    int t = threadIdx.x;
    int slice = blockIdx.x & 3;
    int nb = blockIdx.x >> 2;
    int g = t >> 3;                    // group 0..31
    int j = t & 7;                     // lane in group
    int d = nb * 32 + g;               // node (3125*32 == 100000)

    const uint4* ybase = (const uint4*)(y1s + (size_t)slice * SL_U);
    f32x2 acc2[16];                    // acc2[k] = cols {2k, 2k+1} of 32
#pragma unroll
    for (int c = 0; c < 16; ++c) acc2[c] = (f32x2){0.f, 0.f};

    int st = offs[d], n = count[d];
    for (int i = j; i <= n; i += 8) {            // i==n -> self-loop (one lane)
        int sk = d;
        if (i < n) sk = srcs[st + i];
        uint4 q0 = ybase[(size_t)sk * 2];
        uint4 q1 = ybase[(size_t)sk * 2 + 1];    // same 64B line as q0
        acc2[0]  += __builtin_amdgcn_cvt_pk_f32_fp8(q0.x, false);
        acc2[1]  += __builtin_amdgcn_cvt_pk_f32_fp8(q0.x, true);
        acc2[2]  += __builtin_amdgcn_cvt_pk_f32_fp8(q0.y, false);
        acc2[3]  += __builtin_amdgcn_cvt_pk_f32_fp8(q0.y, true);
        acc2[4]  += __builtin_amdgcn_cvt_pk_f32_fp8(q0.z, false);
        acc2[5]  += __builtin_amdgcn_cvt_pk_f32_fp8(q0.z, true);
        acc2[6]  += __builtin_amdgcn_cvt_pk_f32_fp8(q0.w, false);
        acc2[7]  += __builtin_amdgcn_cvt_pk_f32_fp8(q0.w, true);
        acc2[8]  += __builtin_amdgcn_cvt_pk_f32_fp8(q1.x, false);
        acc2[9]  += __builtin_amdgcn_cvt_pk_f32_fp8(q1.x, true);
        acc2[10] += __builtin_amdgcn_cvt_pk_f32_fp8(q1.y, false);
        acc2[11] += __builtin_amdgcn_cvt_pk_f32_fp8(q1.y, true);
        acc2[12] += __builtin_amdgcn_cvt_pk_f32_fp8(q1.z, false);
        acc2[13] += __builtin_amdgcn_cvt_pk_f32_fp8(q1.z, true);
        acc2[14] += __builtin_amdgcn_cvt_pk_f32_fp8(q1.w, false);
        acc2[15] += __builtin_amdgcn_cvt_pk_f32_fp8(q1.w, true);
    }

    float acc[32];
#pragma unroll
    for (int c = 0; c < 16; ++c) { acc[2 * c] = acc2[c][0]; acc[2 * c + 1] = acc2[c][1]; }

    // reduce-scatter 32 -> 4: lane j ends with cols 4j..4j+3 (r12-verified)
    int hi4 = (j >> 2) & 1, hi2 = (j >> 1) & 1, hi1 = j & 1;
    float v16[16];
#pragma unroll
    for (int c = 0; c < 16; ++c) {
        float keep = hi4 ? acc[c + 16] : acc[c];
        float send = hi4 ? acc[c] : acc[c + 16];
        v16[c] = keep + __shfl_xor(send, 4, 8);
    }
    float v8[8];
#pragma unroll
    for (int c = 0; c < 8; ++c) {
        float keep = hi2 ? v16[c + 8] : v16[c];
        float send = hi2 ? v16[c] : v16[c + 8];
        v8[c] = keep + __shfl_xor(send, 2, 8);
    }
    float v4[4];
#pragma unroll
    for (int c = 0; c < 4; ++c) {
        float keep = hi1 ? v8[c + 4] : v8[c];
        float send = hi1 ? v8[c] : v8[c + 4];
        v4[c] = keep + __shfl_xor(send, 1, 8);
    }

    float ddv = dis[d];
    float4 bv = ((const float4*)b1)[slice * 8 + j];
    float h0 = fmaxf(fmaf(v4[0], ddv, bv.x), 0.0f);
    float h1 = fmaxf(fmaf(v4[1], ddv, bv.y), 0.0f);
    float h2 = fmaxf(fmaf(v4[2], ddv, bv.z), 0.0f);
    float h3 = fmaxf(fmaf(v4[3], ddv, bv.w), 0.0f);

    // partial GEMM2: 4 W2 rows (epilogue load), then class reduce-scatter
    const float* wr = W2 + (size_t)(slice * 32 + 4 * j) * 8;
    float p[8];
#pragma unroll
    for (int c = 0; c < 8; ++c)
        p[c] = h0 * wr[c] + h1 * wr[8 + c] + h2 * wr[16 + c] + h3 * wr[24 + c];
    float q4[4];
#pragma unroll
    for (int c = 0; c < 4; ++c) {
        float keep = hi4 ? p[c + 4] : p[c];
        float send = hi4 ? p[c] : p[c + 4];
        q4[c] = keep + __shfl_xor(send, 4, 8);
    }
    float q2[2];
#pragma unroll
    for (int c = 0; c < 2; ++c) {
        float keep = hi2 ? q4[c + 2] : q4[c];
        float send = hi2 ? q4[c] : q4[c + 2];
        q2[c] = keep + __shfl_xor(send, 2, 8);
    }
    float keep = hi1 ? q2[1] : q2[0];
    float send = hi1 ? q2[0] : q2[1];
    float q = keep + __shfl_xor(send, 1, 8);   // class j

    y2p[(size_t)slice * Y2N + (size_t)d * 8 + j] = q * ddv;  // coalesced store
}

// ---------- pack: sum 4 y2 partials -> bf16x8 rows (16B) ---------------------
__global__ __launch_bounds__(256) void k_pack(const float* __restrict__ y2p,
                                              uint4* __restrict__ y2b) {
    int i = blockIdx.x * 256 + threadIdx.x;    // node
    if (i >= N_NODES) return;
    float4 a = make_float4(0.f, 0.f, 0.f, 0.f);
    float4 b = make_float4(0.f, 0.f, 0.f, 0.f);
#pragma unroll
    for (int s = 0; s < NSL; ++s) {
        const float4* p = (const float4*)(y2p + (size_t)s * Y2N + (size_t)i * 8);
        float4 pa = p[0], pb = p[1];
        a.x += pa.x; a.y += pa.y; a.z += pa.z; a.w += pa.w;
        b.x += pb.x; b.y += pb.y; b.z += pb.z; b.w += pb.w;
    }
    uint4 o;
    o.x = pack_bf16_2(a.x, a.y);
    o.y = pack_bf16_2(a.z, a.w);
    o.z = pack_bf16_2(b.x, b.y);
    o.w = pack_bf16_2(b.z, b.w);
    y2b[i] = o;
}

// ---------- Aggregation 2 (edge-per-lane, bf16 rows) + log_softmax -----------
__global__ __launch_bounds__(256) void k_agg2(const uint4* __restrict__ y2b,
                                              const int* __restrict__ srcs,
                                              const int* __restrict__ offs,
                                              const int* __restrict__ count,
                                              const float* __restrict__ dis,
                                              const float* __restrict__ b2,
                                              float* __restrict__ out) {
    int t = threadIdx.x;
    int g = (blockIdx.x * 256 + t) >> 3;   // node
    int j = t & 7;                         // lane in group
    if (g >= N_NODES) return;
    f32x2 acc2[4];
#pragma unroll
    for (int c = 0; c < 4; ++c) acc2[c] = (f32x2){0.f, 0.f};
    int st = offs[g], n = count[g];
    for (int i = j; i <= n; i += 8) {          // i==n -> self term (one lane)
        int sk = g;
        if (i < n) sk = srcs[st + i];
        uint4 q = y2b[sk];
        acc2[0] += (f32x2){bf_lo(q.x), bf_hi(q.x)};
        acc2[1] += (f32x2){bf_lo(q.y), bf_hi(q.y)};
        acc2[2] += (f32x2){bf_lo(q.z), bf_hi(q.z)};
        acc2[3] += (f32x2){bf_lo(q.w), bf_hi(q.w)};
    }
    float acc[8];
#pragma unroll
    for (int c = 0; c < 4; ++c) { acc[2 * c] = acc2[c][0]; acc[2 * c + 1] = acc2[c][1]; }

    // reduce-scatter 8 -> 1: lane j ends with class j
    int hi4 = (j >> 2) & 1, hi2 = (j >> 1) & 1, hi1 = j & 1;
    float v4[4];
#pragma unroll
    for (int c = 0; c < 4; ++c) {
        float keep = hi4 ? acc[c + 4] : acc[c];
        float send = hi4 ? acc[c] : acc[c + 4];
        v4[c] = keep + __shfl_xor(send, 4, 8);
    }
    float v2[2];
#pragma unroll
    for (int c = 0; c < 2; ++c) {
        float keep = hi2 ? v4[c + 2] : v4[c];
        float send = hi2 ? v4[c] : v4[c + 2];
        v2[c] = keep + __shfl_xor(send, 2, 8);
    }
    float keep = hi1 ? v2[1] : v2[0];
    float send = hi1 ? v2[0] : v2[1];
    float q = keep + __shfl_xor(send, 1, 8);   // class j

    float o = fmaf(q, dis[g], b2[j]);
    float m = o;
#pragma unroll
    for (int k = 1; k < 8; k <<= 1) m = fmaxf(m, __shfl_xor(m, k, 64));
    float e = expf(o - m);
    float ssum = e;
#pragma unroll
    for (int k = 1; k < 8; k <<= 1) ssum += __shfl_xor(ssum, k, 64);
    out[(size_t)g * 8 + j] = (o - m) - logf(ssum);
}

// ---------- host launcher -----------------------------------------------------
extern "C" void kernel_launch(void* const* d_in, const int* in_sizes, int n_in,
                              void* d_out, int out_size, void* d_ws, size_t ws_size,
                              hipStream_t stream) {
    const float* x  = (const float*)d_in[0];
    const int*   ei = (const int*)d_in[1];
    const float* W1 = (const float*)d_in[2];
    const float* b1 = (const float*)d_in[3];
    const float* W2 = (const float*)d_in[4];
    const float* b2 = (const float*)d_in[5];
    float* out = (float*)d_out;
    const int E = in_sizes[1] / 2;     // logical edge count
    const int PB = (E + EPB - 1) / EPB;
    const size_t PADN = (size_t)NBKT * BCAP;   // padded bucket/src capacity

    // workspace layout (all 16B-aligned)
    int*   cursor   = (int*)d_ws;                      // 784 ints
    int*   gflag    = cursor + 784;                    // 4 ints
    int*   count    = gflag + 4;                       // N ints
    int*   offs     = count + N_NODES;                 // N ints
    float* dis      = (float*)(offs + N_NODES);        // N floats
    uint*  bkt_data = (uint*)(dis + N_NODES);          // NBKT*BCAP uints (8MB)
    int*   srcs     = (int*)(bkt_data + PADN);         // NBKT*BCAP ints (8MB)
    uint*  y1s      = (uint*)(srcs + PADN);            // 4 slices * N*8 uints (fp8)
    float* y2p      = (float*)(y1s + (size_t)NSL * SL_U); // 4 * N*8 floats (12.8MB)
    uint4* y2b      = (uint4*)(y2p + (size_t)NSL * Y2N);  // N*16B bf16 rows

    kZ     <<<4, 256, 0, stream>>>(ei, cursor, gflag);
    kP     <<<PB, 256, 0, stream>>>(ei, E, gflag, cursor, bkt_data);
    kB     <<<NBKT, 256, 0, stream>>>(bkt_data, cursor, srcs, count, offs, dis);

    k_gemm1<<<(N_NODES + 63) / 64, 256, 0, stream>>>(x, W1, dis, y1s);
    k_agg1s<<<NSL * 3125, 256, 0, stream>>>(y1s, srcs, offs, count, dis, b1, W2, y2p);
    k_pack <<<(N_NODES + 255) / 256, 256, 0, stream>>>(y2p, y2b);
    k_agg2 <<<(N_NODES * 8 + 255) / 256, 256, 0, stream>>>(y2b, srcs, offs, count, dis, b2, out);
}

// Round 22
// 186.673 us; speedup vs baseline: 1.0415x; 1.0415x over previous
//
#include <hip/hip_runtime.h>

#define N_NODES 100000
#define NBKT 782              // ceil(100000/128) buckets of 128 dst nodes
#define EPB 4096              // edges per partition block (r19: 1.5 blk/CU sweet spot)
#define BCAP 2560             // padded bucket capacity (mean 2048, +11 sigma)
#define SL_U 400000           // uints per fp8 y1 slice = N_NODES*4 (16B rows)
#define Y2N (N_NODES * 8)     // floats per y2 partial slice

typedef unsigned int uint;
typedef unsigned short ushort;
typedef __attribute__((ext_vector_type(8))) short bf16x8;   // 8 bf16 (4 VGPRs)
typedef __attribute__((ext_vector_type(4))) float f32x4;    // MFMA acc
typedef __attribute__((ext_vector_type(2))) float f32x2;    // fp8 unpack pair

union FragU { uint4 u; bf16x8 b; };

// ---------- bf16 helpers ------------------------------------------------------
__device__ __forceinline__ uint pack_bf16_2(float a, float b) {
    uint ua = __float_as_uint(a), ub = __float_as_uint(b);
    ua += 0x7fff + ((ua >> 16) & 1);           // RNE
    ub += 0x7fff + ((ub >> 16) & 1);
    return (ua >> 16) | (ub & 0xffff0000u);
}
__device__ __forceinline__ float bf_lo(uint u) { return __uint_as_float(u << 16); }
__device__ __forceinline__ float bf_hi(uint u) { return __uint_as_float(u & 0xffff0000u); }

// ---------- edge-index access (handles int32 or raw int64 little-endian) ----
__device__ __forceinline__ int edge_at(const int* __restrict__ ei, int idx, int is64) {
    return is64 ? ei[2 * idx] : ei[idx];
}

// ---------- kZ: zero bucket cursors (4 blocks) + dtype probe (block 0) -------
__global__ __launch_bounds__(256) void kZ(const int* __restrict__ ei,
                                          int* __restrict__ cursor,
                                          int* __restrict__ gflag) {
    __shared__ int shp;
    int t = threadIdx.x;
    int b = blockIdx.x;
    for (int i = b * 256 + t; i < NBKT; i += 1024) cursor[i] = 0;
    if (b == 0) {
        if (t == 0) shp = 0;
        __syncthreads();
        int any = 0;
        for (int j = t; j < 4096; j += 256) any |= ei[2 * j + 1];
        if (any) atomicOr(&shp, 1);
        __syncthreads();
        if (t == 0) gflag[0] = shp;            // 0 => int64 little-endian layout
    }
}

// ---------- kP: single-pass partition into PADDED buckets --------------------
__global__ __launch_bounds__(256) void kP(const int* __restrict__ ei, int E,
                                          const int* __restrict__ gflag,
                                          int* __restrict__ cursor,
                                          uint* __restrict__ bkt_data) {
    __shared__ int h[NBKT];                   // per-block histogram / rank
    __shared__ int base[NBKT];                // this block's chunk base
    int t = threadIdx.x;
    int is64 = (gflag[0] == 0);
    for (int i = t; i < NBKT; i += 256) h[i] = 0;
    __syncthreads();
    int lo = blockIdx.x * EPB;
    int end = min(lo + EPB, E);
    for (int e = lo + t; e < end; e += 256) {
        int d = edge_at(ei, E + e, is64);
        atomicAdd(&h[d >> 7], 1);
    }
    __syncthreads();
    for (int i = t; i < NBKT; i += 256) {
        int c = h[i];
        base[i] = c ? atomicAdd(&cursor[i], c) : 0;
    }
    __syncthreads();
    for (int i = t; i < NBKT; i += 256) h[i] = 0;   // reuse as local rank
    __syncthreads();
    for (int e = lo + t; e < end; e += 256) {
        int d = edge_at(ei, E + e, is64);
        int s = edge_at(ei, e, is64);
        int b = d >> 7;
        int r = atomicAdd(&h[b], 1);
        int pos = base[b] + r;
        if (pos < BCAP)                        // 11-sigma guard (never fires)
            bkt_data[(size_t)b * BCAP + pos] = ((uint)s << 7) | (uint)(d & 127);
    }
}

// ---------- kB: per-bucket CSR build + degrees + dis -------------------------
__global__ __launch_bounds__(256) void kB(const uint* __restrict__ bkt_data,
                                          const int* __restrict__ cursor,
                                          int* __restrict__ srcs,
                                          int* __restrict__ count,
                                          int* __restrict__ offs,
                                          float* __restrict__ dis) {
    __shared__ int lc[128];    // local degree
    __shared__ int sc[128];    // inclusive scan
    __shared__ int lcur[128];  // local fill cursor
    int t = threadIdx.x;
    int b = blockIdx.x;
    if (t < 128) { lc[t] = 0; lcur[t] = 0; }
    __syncthreads();
    int start = b * BCAP;
    int n = min(cursor[b], BCAP);
    for (int i = t; i < n; i += 256)
        atomicAdd(&lc[bkt_data[start + i] & 127], 1);
    __syncthreads();
    if (t < 128) sc[t] = lc[t];
    __syncthreads();
    for (int d = 1; d < 128; d <<= 1) {
        int y = 0;
        if (t < 128 && t >= d) y = sc[t - d];
        __syncthreads();
        if (t < 128) sc[t] += y;
        __syncthreads();
    }
    if (t < 128) {
        int node = b * 128 + t;
        if (node < N_NODES) {
            int c = lc[t];
            count[node] = c;
            offs[node] = start + sc[t] - c;
            dis[node] = rsqrtf((float)c + 1.0f);
        }
    }
    __syncthreads();
    for (int i = t; i < n; i += 256) {
        uint rec = bkt_data[start + i];
        int dl = rec & 127;
        int r = atomicAdd(&lcur[dl], 1);
        srcs[start + (sc[dl] - lc[dl]) + r] = rec >> 7;
    }
}

// ---------- GEMM1 (MFMA bf16 -> fp8 store): y1s = e4m3((x@W1)*dis), 8 slices -
__global__ __launch_bounds__(256) void k_gemm1(const float* __restrict__ x,
                                               const float* __restrict__ W,
                                               const float* __restrict__ dis,
                                               uint* __restrict__ y1s) {
    __shared__ uint4 WtA[2048];               // 32 KB
    char* wt = (char*)WtA;
    int t = threadIdx.x;

    const float4* W4 = (const float4*)W;
#pragma unroll
    for (int ii = 0; ii < 4; ++ii) {
        int tile = t + 256 * ii;              // 1024 (nq,kq) 4x4 tiles
        int nq = tile >> 5, kq = tile & 31;
        float4 r0 = W4[(4 * kq + 0) * 32 + nq];
        float4 r1 = W4[(4 * kq + 1) * 32 + nq];
        float4 r2 = W4[(4 * kq + 2) * 32 + nq];
        float4 r3 = W4[(4 * kq + 3) * 32 + nq];
        const float* p0 = (const float*)&r0;
        const float* p1 = (const float*)&r1;
        const float* p2 = (const float*)&r2;
        const float* p3 = (const float*)&r3;
#pragma unroll
        for (int cc = 0; cc < 4; ++cc) {
            int n = 4 * nq + cc;
            uint2 v;
            v.x = pack_bf16_2(p0[cc], p1[cc]);
            v.y = pack_bf16_2(p2[cc], p3[cc]);
            *(uint2*)(wt + n * 256 + (((kq >> 1) ^ (n & 7)) << 4) + ((kq & 1) << 3)) = v;
        }
    }
    __syncthreads();

    int w = t >> 6, lane = t & 63;
    int m = lane & 15, kg = lane >> 4;
    int row0 = blockIdx.x * 64 + 16 * w;

    int arow = row0 + m;
    bool av = arow < N_NODES;
    const float4* xr = (const float4*)(x + (size_t)arow * 128);
    float4 z4 = make_float4(0.f, 0.f, 0.f, 0.f);
    FragU af[4];
#pragma unroll
    for (int kf = 0; kf < 4; ++kf) {
        float4 g0 = av ? xr[8 * kf + 2 * kg]     : z4;
        float4 g1 = av ? xr[8 * kf + 2 * kg + 1] : z4;
        const float* a0 = (const float*)&g0;
        const float* a1 = (const float*)&g1;
        af[kf].u.x = pack_bf16_2(a0[0], a0[1]);
        af[kf].u.y = pack_bf16_2(a0[2], a0[3]);
        af[kf].u.z = pack_bf16_2(a1[0], a1[1]);
        af[kf].u.w = pack_bf16_2(a1[2], a1[3]);
    }

    int crow = row0 + 4 * kg;
    float dd[4];
#pragma unroll
    for (int rr = 0; rr < 4; ++rr)
        dd[rr] = (crow + rr < N_NODES) ? dis[crow + rr] : 0.0f;

    char* yb = (char*)y1s;
#pragma unroll
    for (int ct = 0; ct < 8; ++ct) {          // col-tile == slice (16 cols)
        f32x4 acc = {0.f, 0.f, 0.f, 0.f};
#pragma unroll
        for (int kf = 0; kf < 4; ++kf) {
            int n = 16 * ct + m;              // B col = lane&15
            bf16x8 bw = *(const bf16x8*)(wt + n * 256 + ((((kf << 2) | kg) ^ (n & 7)) << 4));
            acc = __builtin_amdgcn_mfma_f32_16x16x32_bf16(af[kf].b, bw, acc, 0, 0, 0);
        }
#pragma unroll
        for (int rr = 0; rr < 4; ++rr) {
            float v = acc[rr] * dd[rr];
            float p = __shfl_xor(v, 1, 64);   // partner col (odd)
            if (!(lane & 1)) {
                int grow = crow + rr;
                if (grow < N_NODES) {
                    uint pk = __builtin_amdgcn_cvt_pk_fp8_f32(v, p, 0, false);
                    *(ushort*)(yb + (size_t)ct * (SL_U * 4) + grow * 16 + m) = (ushort)pk;
                }
            }
        }
    }
}

// ---------- Aggregation 1 (8 fp8 slices) + partial GEMM2 ---------------------
// NO ATOMICS: partial y2 -> XCD-private y2p[slice] via coalesced plain stores
// (r20: -5us vs cross-XCD atomic RMW). 16B rows / 32 VGPR / 76% occ is the
// measured optimum (r7/r12/r21 bracket both directions).
__global__ __launch_bounds__(256) void k_agg1s(const uint* __restrict__ y1s,
                                               const int* __restrict__ srcs,
                                               const int* __restrict__ offs,
                                               const int* __restrict__ count,
                                               const float* __restrict__ dis,
                                               const float* __restrict__ b1,
                                               const float* __restrict__ W2,
                                               float* __restrict__ y2p) {
    int t = threadIdx.x;
    int slice = blockIdx.x & 7;
    int nb = blockIdx.x >> 3;
    int g = t >> 3;                    // group 0..31
    int j = t & 7;                     // lane in group
    int d = nb * 32 + g;               // node (3125*32 == 100000)

    // W2 rows for this lane (fixed): rows slice*16+2j, slice*16+2j+1
    float w0[8], w1[8];
    const float* wr0 = W2 + (size_t)(slice * 16 + 2 * j) * 8;
#pragma unroll
    for (int c = 0; c < 8; ++c) { w0[c] = wr0[c]; w1[c] = wr0[8 + c]; }

    const uint4* ybase = (const uint4*)(y1s + (size_t)slice * SL_U);
    f32x2 acc2[8];                     // acc2[k] = cols {2k, 2k+1}
#pragma unroll
    for (int c = 0; c < 8; ++c) acc2[c] = (f32x2){0.f, 0.f};

#define ACCUM_Q(q)                                                             \
    do {                                                                       \
        acc2[0] += __builtin_amdgcn_cvt_pk_f32_fp8((q).x, false);              \
        acc2[1] += __builtin_amdgcn_cvt_pk_f32_fp8((q).x, true);               \
        acc2[2] += __builtin_amdgcn_cvt_pk_f32_fp8((q).y, false);              \
        acc2[3] += __builtin_amdgcn_cvt_pk_f32_fp8((q).y, true);               \
        acc2[4] += __builtin_amdgcn_cvt_pk_f32_fp8((q).z, false);              \
        acc2[5] += __builtin_amdgcn_cvt_pk_f32_fp8((q).z, true);               \
        acc2[6] += __builtin_amdgcn_cvt_pk_f32_fp8((q).w, false);              \
        acc2[7] += __builtin_amdgcn_cvt_pk_f32_fp8((q).w, true);               \
    } while (0)

    int st = offs[d], n = count[d];
    int i = j;
    if (i <= n) {                                // i==n -> self-loop (one lane)
        int sk = (i < n) ? srcs[st + i] : d;
        uint4 q = ybase[sk];
        for (i += 8; i <= n; i += 8) {
            int sk2 = (i < n) ? srcs[st + i] : d;
            uint4 qn = ybase[sk2];               // prefetch next (in flight)
            ACCUM_Q(q);
            q = qn;
        }
        ACCUM_Q(q);
    }
#undef ACCUM_Q

    float acc[16];
#pragma unroll
    for (int c = 0; c < 8; ++c) { acc[2 * c] = acc2[c][0]; acc[2 * c + 1] = acc2[c][1]; }

    // reduce-scatter: lane j ends with cols 2j (v2[0]) and 2j+1 (v2[1])
    int hi4 = (j >> 2) & 1, hi2 = (j >> 1) & 1, hi1 = j & 1;
    float v8[8];
#pragma unroll
    for (int c = 0; c < 8; ++c) {
        float keep = hi4 ? acc[c + 8] : acc[c];
        float send = hi4 ? acc[c] : acc[c + 8];
        v8[c] = keep + __shfl_xor(send, 4, 8);
    }
    float v4[4];
#pragma unroll
    for (int c = 0; c < 4; ++c) {
        float keep = hi2 ? v8[c + 4] : v8[c];
        float send = hi2 ? v8[c] : v8[c + 4];
        v4[c] = keep + __shfl_xor(send, 2, 8);
    }
    float v2[2];
#pragma unroll
    for (int c = 0; c < 2; ++c) {
        float keep = hi1 ? v4[c + 2] : v4[c];
        float send = hi1 ? v4[c] : v4[c + 2];
        v2[c] = keep + __shfl_xor(send, 1, 8);
    }

    float ddv = dis[d];
    float2 b = ((const float2*)b1)[slice * 8 + j];
    float h0 = fmaxf(fmaf(v2[0], ddv, b.x), 0.0f);
    float h1 = fmaxf(fmaf(v2[1], ddv, b.y), 0.0f);

    float p[8];
#pragma unroll
    for (int c = 0; c < 8; ++c) p[c] = h0 * w0[c] + h1 * w1[c];
    float q4[4];
#pragma unroll
    for (int c = 0; c < 4; ++c) {
        float keep = hi4 ? p[c + 4] : p[c];
        float send = hi4 ? p[c] : p[c + 4];
        q4[c] = keep + __shfl_xor(send, 4, 8);
    }
    float q2[2];
#pragma unroll
    for (int c = 0; c < 2; ++c) {
        float keep = hi2 ? q4[c + 2] : q4[c];
        float send = hi2 ? q4[c] : q4[c + 2];
        q2[c] = keep + __shfl_xor(send, 2, 8);
    }
    float keep = hi1 ? q2[1] : q2[0];
    float send = hi1 ? q2[0] : q2[1];
    float q = keep + __shfl_xor(send, 1, 8);   // class j

    y2p[(size_t)slice * Y2N + (size_t)d * 8 + j] = q * ddv;  // coalesced store
}

// ---------- pack: sum 8 y2 partials -> bf16x8 rows (16B) ---------------------
__global__ __launch_bounds__(256) void k_pack(const float* __restrict__ y2p,
                                              uint4* __restrict__ y2b) {
    int i = blockIdx.x * 256 + threadIdx.x;    // node
    if (i >= N_NODES) return;
    float4 a = make_float4(0.f, 0.f, 0.f, 0.f);
    float4 b = make_float4(0.f, 0.f, 0.f, 0.f);
#pragma unroll
    for (int s = 0; s < 8; ++s) {
        const float4* p = (const float4*)(y2p + (size_t)s * Y2N + (size_t)i * 8);
        float4 pa = p[0], pb = p[1];
        a.x += pa.x; a.y += pa.y; a.z += pa.z; a.w += pa.w;
        b.x += pb.x; b.y += pb.y; b.z += pb.z; b.w += pb.w;
    }
    uint4 o;
    o.x = pack_bf16_2(a.x, a.y);
    o.y = pack_bf16_2(a.z, a.w);
    o.z = pack_bf16_2(b.x, b.y);
    o.w = pack_bf16_2(b.z, b.w);
    y2b[i] = o;
}

// ---------- Aggregation 2 (edge-per-lane, bf16 rows) + log_softmax -----------
__global__ __launch_bounds__(256) void k_agg2(const uint4* __restrict__ y2b,
                                              const int* __restrict__ srcs,
                                              const int* __restrict__ offs,
                                              const int* __restrict__ count,
                                              const float* __restrict__ dis,
                                              const float* __restrict__ b2,
                                              float* __restrict__ out) {
    int t = threadIdx.x;
    int g = (blockIdx.x * 256 + t) >> 3;   // node
    int j = t & 7;                         // lane in group
    if (g >= N_NODES) return;
    f32x2 acc2[4];
#pragma unroll
    for (int c = 0; c < 4; ++c) acc2[c] = (f32x2){0.f, 0.f};
    int st = offs[g], n = count[g];
    for (int i = j; i <= n; i += 8) {          // i==n -> self term (one lane)
        int sk = g;
        if (i < n) sk = srcs[st + i];
        uint4 q = y2b[sk];
        acc2[0] += (f32x2){bf_lo(q.x), bf_hi(q.x)};
        acc2[1] += (f32x2){bf_lo(q.y), bf_hi(q.y)};
        acc2[2] += (f32x2){bf_lo(q.z), bf_hi(q.z)};
        acc2[3] += (f32x2){bf_lo(q.w), bf_hi(q.w)};
    }
    float acc[8];
#pragma unroll
    for (int c = 0; c < 4; ++c) { acc[2 * c] = acc2[c][0]; acc[2 * c + 1] = acc2[c][1]; }

    // reduce-scatter 8 -> 1: lane j ends with class j
    int hi4 = (j >> 2) & 1, hi2 = (j >> 1) & 1, hi1 = j & 1;
    float v4[4];
#pragma unroll
    for (int c = 0; c < 4; ++c) {
        float keep = hi4 ? acc[c + 4] : acc[c];
        float send = hi4 ? acc[c] : acc[c + 4];
        v4[c] = keep + __shfl_xor(send, 4, 8);
    }
    float v2[2];
#pragma unroll
    for (int c = 0; c < 2; ++c) {
        float keep = hi2 ? v4[c + 2] : v4[c];
        float send = hi2 ? v4[c] : v4[c + 2];
        v2[c] = keep + __shfl_xor(send, 2, 8);
    }
    float keep = hi1 ? v2[1] : v2[0];
    float send = hi1 ? v2[0] : v2[1];
    float q = keep + __shfl_xor(send, 1, 8);   // class j

    float o = fmaf(q, dis[g], b2[j]);
    float m = o;
#pragma unroll
    for (int k = 1; k < 8; k <<= 1) m = fmaxf(m, __shfl_xor(m, k, 64));
    float e = expf(o - m);
    float ssum = e;
#pragma unroll
    for (int k = 1; k < 8; k <<= 1) ssum += __shfl_xor(ssum, k, 64);
    out[(size_t)g * 8 + j] = (o - m) - logf(ssum);
}

// ---------- host launcher -----------------------------------------------------
extern "C" void kernel_launch(void* const* d_in, const int* in_sizes, int n_in,
                              void* d_out, int out_size, void* d_ws, size_t ws_size,
                              hipStream_t stream) {
    const float* x  = (const float*)d_in[0];
    const int*   ei = (const int*)d_in[1];
    const float* W1 = (const float*)d_in[2];
    const float* b1 = (const float*)d_in[3];
    const float* W2 = (const float*)d_in[4];
    const float* b2 = (const float*)d_in[5];
    float* out = (float*)d_out;
    const int E = in_sizes[1] / 2;     // logical edge count
    const int PB = (E + EPB - 1) / EPB;
    const size_t PADN = (size_t)NBKT * BCAP;   // padded bucket/src capacity

    // workspace layout (all 16B-aligned)
    int*   cursor   = (int*)d_ws;                      // 784 ints
    int*   gflag    = cursor + 784;                    // 4 ints
    int*   count    = gflag + 4;                       // N ints
    int*   offs     = count + N_NODES;                 // N ints
    float* dis      = (float*)(offs + N_NODES);        // N floats
    uint*  bkt_data = (uint*)(dis + N_NODES);          // NBKT*BCAP uints (8MB)
    int*   srcs     = (int*)(bkt_data + PADN);         // NBKT*BCAP ints (8MB)
    uint*  y1s      = (uint*)(srcs + PADN);            // 8 slices * N*4 uints (fp8)
    float* y2p      = (float*)(y1s + (size_t)8 * SL_U);   // 8 * N*8 floats (25.6MB)
    uint4* y2b      = (uint4*)(y2p + (size_t)8 * Y2N);    // N*16B bf16 rows

    kZ     <<<4, 256, 0, stream>>>(ei, cursor, gflag);
    kP     <<<PB, 256, 0, stream>>>(ei, E, gflag, cursor, bkt_data);
    kB     <<<NBKT, 256, 0, stream>>>(bkt_data, cursor, srcs, count, offs, dis);

    k_gemm1<<<(N_NODES + 63) / 64, 256, 0, stream>>>(x, W1, dis, y1s);
    k_agg1s<<<8 * 3125, 256, 0, stream>>>(y1s, srcs, offs, count, dis, b1, W2, y2p);
    k_pack <<<(N_NODES + 255) / 256, 256, 0, stream>>>(y2p, y2b);
    k_agg2 <<<(N_NODES * 8 + 255) / 256, 256, 0, stream>>>(y2b, srcs, offs, count, dis, b2, out);
}